// Round 3
// baseline (416.267 us; speedup 1.0000x reference)
//
#include <hip/hip_runtime.h>
#include <hip/hip_bf16.h>
#include <math.h>

#define BB 32768
#define EE 16
#define HH 128
#define KP 160          // padded K: 16 x + 128 h + 16 zeros
#define XS 168          // xh row stride (bf16 elems): 168*2B=336B -> bank-spread, 16B-aligned
#define OBS 8
#define NSTEP 19
#define TPB 1024
#define MROWS 64        // batch rows per block
#define KT 5            // K-tiles of 32

typedef short s16x8 __attribute__((ext_vector_type(8)));   // 8 bf16 (4 VGPRs), MFMA A/B frag
typedef float f32x4 __attribute__((ext_vector_type(4)));   // MFMA C/D frag

__device__ __forceinline__ float sigm(float x){ return __builtin_amdgcn_rcpf(1.0f + __expf(-x)); }
__device__ __forceinline__ float ftanh(float x){ float e = __expf(-2.f*x); return (1.f-e)*__builtin_amdgcn_rcpf(1.f+e); }
// NOTE: must stay EXACTLY __float2bfloat16 -- replacing with a bit-trick RNE changed the
// rounding realization and blew absmax past threshold (R1/R2 failures). Do not touch.
__device__ __forceinline__ unsigned short f2b(float x){
    __hip_bfloat16 h = __float2bfloat16(x);
    return *reinterpret_cast<unsigned short*>(&h);
}
__device__ __forceinline__ float b2f_(unsigned short u){ return __uint_as_float(((unsigned int)u) << 16); }

// Pack W_cat = [W_ih | W_hh] (K=144, zero-pad to 160) into MFMA A-operand fragment order,
// split into bf16 hi + lo.  Frag (JT 0..31, kt 0..4): lane l, elem j holds
//   W_cat[k = kt*32 + (l>>4)*8 + j][jg = JT*16 + (l&15)],  jg = 4*j_hidden + gate.
__global__ __launch_bounds__(256) void k_prep(
    const float* __restrict__ W_ih, const float* __restrict__ W_hh,
    unsigned short* __restrict__ Whi, unsigned short* __restrict__ Wlo)
{
    int idx = blockIdx.x * 256 + threadIdx.x;      // exactly 32*5*64*8 = 81920 threads
    int j    = idx & 7;
    int lane = (idx >> 3) & 63;
    int kt   = (idx >> 9) % KT;
    int JT   = idx / (KT * 512);
    int k  = kt * 32 + ((lane >> 4) << 3) + j;
    int jg = JT * 16 + (lane & 15);
    int col = (jg & 3) * HH + (jg >> 2);           // original gate row: g*128 + j_hidden
    float wv = 0.f;
    if (k < EE)            wv = W_ih[col * EE + k];
    else if (k < EE + HH)  wv = W_hh[col * HH + (k - EE)];
    unsigned short hi = f2b(wv);
    Whi[idx] = hi;
    Wlo[idx] = f2b(wv - b2f_(hi));
}

// Row-half software pipeline: rows A = 0..31, rows B = 32..63.
//   P1: GEMM_A(s)      (MFMA) || readout_B(s-1)+embed_B (waves 8-15, VALU)
//   P2: GEMM_B(s)      (MFMA) || cell_A(s)+h-write_A    (all waves, VALU)
//   P3: cell_B+h-write_B      || readout_A(s)+embed_A   (waves 0-7)
// Same 3 barriers/step as lockstep version; fp ops bitwise-identical (pure reordering of
// independent work).  Occupancy attrs unchanged (waves_per_eu(4,4), ~115 live regs).
__global__ __attribute__((amdgpu_flat_work_group_size(TPB, TPB)))
           __attribute__((amdgpu_waves_per_eu(4, 4)))
void k_lstm(
    const float* __restrict__ obs,
    const float* __restrict__ W_emb, const float* __restrict__ b_emb,
    const float* __restrict__ b_ih,  const float* __restrict__ b_hh,
    const unsigned short* __restrict__ Whi, const unsigned short* __restrict__ Wlo,
    const float* __restrict__ W_out, const float* __restrict__ b_out,
    float* __restrict__ out)
{
    __shared__ unsigned short xhh[MROWS * XS];   // bf16 hi of [x(16)|h(128)|0(16)|pad]
    __shared__ unsigned short xhl[MROWS * XS];   // bf16 lo
    __shared__ float wout[2 * HH];
    __shared__ float wemb[EE * 2];
    __shared__ float bemb[EE];

    const int t    = threadIdx.x;
    const int lane = t & 63;
    const int w    = t >> 6;                     // wave 0..15: gate-cols jg in [w*32,(w+1)*32)
    const int row0 = blockIdx.x * MROWS;

    if (t < 2 * HH) wout[t] = W_out[t];          // rows 0,1 of W_out (contiguous)
    if (t < EE * 2) wemb[t] = W_emb[t];
    if (t < EE)     bemb[t] = b_emb[t];
    for (int i = t; i < MROWS * XS; i += TPB) { xhh[i] = 0; xhl[i] = 0; }

    // per-lane gate biases: acc[mt] reg r <-> jg = (2w+mt)*16 + (lane>>4)*4 + r
    f32x4 bias[2];
#pragma unroll
    for (int mt = 0; mt < 2; mt++)
#pragma unroll
        for (int r = 0; r < 4; r++) {
            int jg  = (2 * w + mt) * 16 + ((lane >> 4) << 2) + r;
            int col = (jg & 3) * HH + (jg >> 2);
            bias[mt][r] = b_ih[col] + b_hh[col];
        }
    const float bo0 = b_out[0], bo1 = b_out[1];

    // readout/embed mapping: row = t>>4 (64 rows), rp = t&15 (16-way partials / 16 embed dims)
    const int rrow = t >> 4;
    const int rp   = t & 15;
    const int grow = row0 + rrow;
    const bool halfB = (rrow >= 32);             // wave-uniform (waves 8-15)

    const unsigned short* aHi = Whi + ((size_t)(2 * w) * KT) * 512 + (lane << 3);
    const unsigned short* aLo = Wlo + ((size_t)(2 * w) * KT) * 512 + (lane << 3);

    float c8[2][4];
#pragma unroll
    for (int mt = 0; mt < 2; mt++)
#pragma unroll
        for (int nt = 0; nt < 4; nt++) c8[mt][nt] = 0.f;
    float pl0 = 0.f, pl1 = 0.f;                  // p_last (per-row, maintained by all 16 rp-threads)

    __syncthreads();

    // initial embed x[0] from obs delta: thread (rrow, rp=e), covers both halves
    {
        float d0 = obs[(size_t)1 * BB * 2 + grow * 2 + 0] - obs[(size_t)0 * BB * 2 + grow * 2 + 0];
        float d1 = obs[(size_t)1 * BB * 2 + grow * 2 + 1] - obs[(size_t)0 * BB * 2 + grow * 2 + 1];
        float v = bemb[rp] + d0 * wemb[2 * rp] + d1 * wemb[2 * rp + 1];
        v = v > 0.f ? v : 0.f;
        unsigned short hi = f2b(v);
        xhh[rrow * XS + rp] = hi;
        xhl[rrow * XS + rp] = f2b(v - b2f_(hi));
    }
    __syncthreads();

    // readout + position + next-step embed for this thread's own row, at step sidx.
    // Identical fp text to the lockstep baseline (s -> sidx).
    auto readout_embed = [&](int sidx) {
        const unsigned short* ph = &xhh[rrow * XS + EE + (rp << 3)];
        const unsigned short* pq = &xhl[rrow * XS + EE + (rp << 3)];
        s16x8 uh = *(const s16x8*)ph;
        s16x8 ul = *(const s16x8*)pq;
        float4 w0a = *(const float4*)&wout[(rp << 3)];
        float4 w0b = *(const float4*)&wout[(rp << 3) + 4];
        float4 w1a = *(const float4*)&wout[HH + (rp << 3)];
        float4 w1b = *(const float4*)&wout[HH + (rp << 3) + 4];
        float hv[8];
#pragma unroll
        for (int q = 0; q < 8; q++)
            hv[q] = b2f_((unsigned short)uh[q]) + b2f_((unsigned short)ul[q]);
        float r0 = hv[0]*w0a.x + hv[1]*w0a.y + hv[2]*w0a.z + hv[3]*w0a.w
                 + hv[4]*w0b.x + hv[5]*w0b.y + hv[6]*w0b.z + hv[7]*w0b.w;
        float r1 = hv[0]*w1a.x + hv[1]*w1a.y + hv[2]*w1a.z + hv[3]*w1a.w
                 + hv[4]*w1b.x + hv[5]*w1b.y + hv[6]*w1b.z + hv[7]*w1b.w;
#pragma unroll
        for (int m = 1; m < 16; m <<= 1) {
            r0 += __shfl_xor(r0, m, 64);
            r1 += __shfl_xor(r1, m, 64);
        }
        float base0, base1;
        if (sidx < OBS) {
            base0 = obs[(size_t)(sidx + 1) * BB * 2 + grow * 2 + 0];
            base1 = obs[(size_t)(sidx + 1) * BB * 2 + grow * 2 + 1];
        } else {
            base0 = pl0; base1 = pl1;
        }
        float pos0 = base0 + r0 + bo0;
        float pos1 = base1 + r1 + bo1;
        if (rp == 0) {
            out[((size_t)sidx * BB + grow) * 2 + 0] = pos0;
            out[((size_t)sidx * BB + grow) * 2 + 1] = pos1;
        }
        if (sidx + 1 < NSTEP) {
            float d0, d1;
            if (sidx + 1 < OBS) {
                d0 = obs[(size_t)(sidx + 2) * BB * 2 + grow * 2 + 0] - obs[(size_t)(sidx + 1) * BB * 2 + grow * 2 + 0];
                d1 = obs[(size_t)(sidx + 2) * BB * 2 + grow * 2 + 1] - obs[(size_t)(sidx + 1) * BB * 2 + grow * 2 + 1];
            } else {
                d0 = pos0 - pl0;            // p_last_new - p_prev_new
                d1 = pos1 - pl1;
            }
            float v = bemb[rp] + d0 * wemb[2 * rp] + d1 * wemb[2 * rp + 1];
            v = v > 0.f ? v : 0.f;
            unsigned short hi = f2b(v);
            xhh[rrow * XS + rp] = hi;       // x-region write, own row; disjoint from h region
            xhl[rrow * XS + rp] = f2b(v - b2f_(hi));
        }
        pl0 = pos0; pl1 = pos1;
    };

    f32x4 accA[2][2], accB[2][2];

#pragma unroll 1
    for (int s = 0; s < NSTEP; s++) {
        // ================= P1: GEMM_A(s) || readout_B(s-1) =================
#pragma unroll
        for (int mt = 0; mt < 2; mt++)
#pragma unroll
            for (int nt = 0; nt < 2; nt++) accA[mt][nt] = bias[mt];

#pragma unroll 1
        for (int kt = 0; kt < KT; kt++) {
            const int fo0 = (0 * KT + kt) << 9;
            const int fo1 = (1 * KT + kt) << 9;
            s16x8 ah0 = *(const s16x8*)(aHi + fo0);
            s16x8 ah1 = *(const s16x8*)(aHi + fo1);
            s16x8 al0 = *(const s16x8*)(aLo + fo0);
            s16x8 al1 = *(const s16x8*)(aLo + fo1);
            const int koff = (kt << 5) + ((lane >> 4) << 3);
            const unsigned short* bhp = &xhh[(lane & 15) * XS + koff];
            const unsigned short* blp = &xhl[(lane & 15) * XS + koff];
#pragma unroll
            for (int nt = 0; nt < 2; nt++) {
                s16x8 bH = *(const s16x8*)(bhp + nt * 16 * XS);      // rows 0..31
                accA[0][nt] = __builtin_amdgcn_mfma_f32_16x16x32_bf16(ah0, bH, accA[0][nt], 0, 0, 0);
                accA[1][nt] = __builtin_amdgcn_mfma_f32_16x16x32_bf16(ah1, bH, accA[1][nt], 0, 0, 0);
                accA[0][nt] = __builtin_amdgcn_mfma_f32_16x16x32_bf16(al0, bH, accA[0][nt], 0, 0, 0);
                accA[1][nt] = __builtin_amdgcn_mfma_f32_16x16x32_bf16(al1, bH, accA[1][nt], 0, 0, 0);
            }
#pragma unroll
            for (int nt = 0; nt < 2; nt++) {
                s16x8 bL = *(const s16x8*)(blp + nt * 16 * XS);
                accA[0][nt] = __builtin_amdgcn_mfma_f32_16x16x32_bf16(ah0, bL, accA[0][nt], 0, 0, 0);
                accA[1][nt] = __builtin_amdgcn_mfma_f32_16x16x32_bf16(ah1, bL, accA[1][nt], 0, 0, 0);
            }
        }
        if (s > 0 && halfB) readout_embed(s - 1);   // waves 8-15: out[s-1] rows B, x_B(s)

        __syncthreads();   // B1: x_B(s) visible; all GEMM_A readers done (h_A writable)

        // ================= P2: GEMM_B(s) || cell_A + h-write_A =================
#pragma unroll
        for (int mt = 0; mt < 2; mt++)
#pragma unroll
            for (int nt = 0; nt < 2; nt++) accB[mt][nt] = bias[mt];

#pragma unroll 1
        for (int kt = 0; kt < KT; kt++) {
            const int fo0 = (0 * KT + kt) << 9;
            const int fo1 = (1 * KT + kt) << 9;
            s16x8 ah0 = *(const s16x8*)(aHi + fo0);
            s16x8 ah1 = *(const s16x8*)(aHi + fo1);
            s16x8 al0 = *(const s16x8*)(aLo + fo0);
            s16x8 al1 = *(const s16x8*)(aLo + fo1);
            const int koff = (kt << 5) + ((lane >> 4) << 3);
            const unsigned short* bhp = &xhh[(lane & 15) * XS + koff];
            const unsigned short* blp = &xhl[(lane & 15) * XS + koff];
#pragma unroll
            for (int nt = 0; nt < 2; nt++) {
                s16x8 bH = *(const s16x8*)(bhp + (2 + nt) * 16 * XS);  // rows 32..63
                accB[0][nt] = __builtin_amdgcn_mfma_f32_16x16x32_bf16(ah0, bH, accB[0][nt], 0, 0, 0);
                accB[1][nt] = __builtin_amdgcn_mfma_f32_16x16x32_bf16(ah1, bH, accB[1][nt], 0, 0, 0);
                accB[0][nt] = __builtin_amdgcn_mfma_f32_16x16x32_bf16(al0, bH, accB[0][nt], 0, 0, 0);
                accB[1][nt] = __builtin_amdgcn_mfma_f32_16x16x32_bf16(al1, bH, accB[1][nt], 0, 0, 0);
            }
#pragma unroll
            for (int nt = 0; nt < 2; nt++) {
                s16x8 bL = *(const s16x8*)(blp + (2 + nt) * 16 * XS);
                accB[0][nt] = __builtin_amdgcn_mfma_f32_16x16x32_bf16(ah0, bL, accB[0][nt], 0, 0, 0);
                accB[1][nt] = __builtin_amdgcn_mfma_f32_16x16x32_bf16(ah1, bL, accB[1][nt], 0, 0, 0);
            }
        }
        // cell_A: rows 0..31 (nt 0,1) -- interleaves with GEMM_B on the VALU pipe
#pragma unroll
        for (int mt = 0; mt < 2; mt++)
#pragma unroll
            for (int nt = 0; nt < 2; nt++) {
                f32x4 g = accA[mt][nt];
                float cn = sigm(g[1]) * c8[mt][nt] + sigm(g[0]) * ftanh(g[2]);
                c8[mt][nt] = cn;
                float h = sigm(g[3]) * ftanh(cn);
                int row = nt * 16 + (lane & 15);
                int j   = 8 * w + mt * 4 + (lane >> 4);
                unsigned short hi = f2b(h);
                xhh[row * XS + EE + j] = hi;
                xhl[row * XS + EE + j] = f2b(h - b2f_(hi));
            }

        __syncthreads();   // B2: h_A(s) visible; all GEMM_B readers done (h_B writable)

        // ================= P3: cell_B + h-write_B || readout_A(s) =================
#pragma unroll
        for (int mt = 0; mt < 2; mt++)
#pragma unroll
            for (int nt = 0; nt < 2; nt++) {
                f32x4 g = accB[mt][nt];
                float cn = sigm(g[1]) * c8[mt][2 + nt] + sigm(g[0]) * ftanh(g[2]);
                c8[mt][2 + nt] = cn;
                float h = sigm(g[3]) * ftanh(cn);
                int row = (2 + nt) * 16 + (lane & 15);
                int j   = 8 * w + mt * 4 + (lane >> 4);
                unsigned short hi = f2b(h);
                xhh[row * XS + EE + j] = hi;
                xhl[row * XS + EE + j] = f2b(h - b2f_(hi));
            }
        if (!halfB) readout_embed(s);               // waves 0-7: out[s] rows A, x_A(s+1)

        __syncthreads();   // B3: h_B(s), x_A(s+1) visible for next P1
    }

    // epilogue: last-step readout for rows B (h_B(18) visible after final B3)
    if (halfB) readout_embed(NSTEP - 1);
}

extern "C" void kernel_launch(void* const* d_in, const int* in_sizes, int n_in,
                              void* d_out, int out_size, void* d_ws, size_t ws_size,
                              hipStream_t stream)
{
    const float* obs   = (const float*)d_in[0];
    const float* W_emb = (const float*)d_in[1];
    const float* b_emb = (const float*)d_in[2];
    const float* W_ih  = (const float*)d_in[3];
    const float* b_ih  = (const float*)d_in[4];
    const float* W_hh  = (const float*)d_in[5];
    const float* b_hh  = (const float*)d_in[6];
    const float* W_out = (const float*)d_in[7];
    const float* b_out = (const float*)d_in[8];
    float* out = (float*)d_out;

    unsigned short* Whi = (unsigned short*)d_ws;        // 32*5*64*8 = 81920 bf16
    unsigned short* Wlo = Whi + 32 * KT * 64 * 8;       // another 81920

    hipLaunchKernelGGL(k_prep, dim3(32 * KT * 64 * 8 / 256), dim3(256), 0, stream,
                       W_ih, W_hh, Whi, Wlo);

    hipLaunchKernelGGL(k_lstm, dim3(BB / MROWS), dim3(TPB), 0, stream,
                       obs, W_emb, b_emb, b_ih, b_hh, Whi, Wlo, W_out, b_out, out);
}